// Round 4
// baseline (1704.909 us; speedup 1.0000x reference)
//
#include <hip/hip_runtime.h>

// out[b,o,n] = sum_{k,c} input[b,c,n] * weight[o,k,c] * score[b,k,n]
// B=8, C_IN=16, C_OUT=16, K=4, N=524288. All fp32.
// Compute floor ~58us (9.1 GFLOP @ 157 TF), HBM floor ~68us (426 MB @ 6.3 TB/s).
//
// Round 3 lesson: with x[16] held across the o-loop, the compiler chose 64 VGPR
// and re-materialized the input loads per o-iteration (loads are rematerializable)
// -> 4.3 GB of L1 traffic, L1-BW-bound at ~35 TB/s. Fix: invert the loop nest so
// the long-lived state is acc[16] (computed, NOT rematerializable) and each input
// value is transient and loaded exactly once.

constexpr int B     = 8;
constexpr int C_IN  = 16;
constexpr int C_OUT = 16;
constexpr int KK    = 4;
constexpr int N     = 524288;
constexpr int N4    = N / 4;   // float4 elements per (b, channel) row

typedef float vfloat4 __attribute__((ext_vector_type(4)));  // native vector for nt-store

__global__ __launch_bounds__(256, 3) void
TransformConv1d_39264591020709_kernel(const float* __restrict__ in,
                                      const float* __restrict__ w,
                                      const float* __restrict__ sc,
                                      float* __restrict__ out) {
    const int idx = blockIdx.x * blockDim.x + threadIdx.x;   // 0 .. B*N4-1
    const int b  = idx >> 17;        // idx / N4  (N4 = 131072 = 2^17)
    const int n4 = idx & (N4 - 1);   // idx % N4

    const float4* inB  = reinterpret_cast<const float4*>(in)  + (size_t)b * C_IN * N4;
    const float4* scB  = reinterpret_cast<const float4*>(sc)  + (size_t)b * KK   * N4;
    float4*       outB = reinterpret_cast<float4*>(out)       + (size_t)b * C_OUT * N4;

    // Scores: 4 float4 = 16 VGPRs, live for the whole kernel.
    float4 a[KK];
#pragma unroll
    for (int k = 0; k < KK; ++k) a[k] = scB[k * N4 + n4];

    // Accumulators for ALL 16 output channels: 64 VGPRs of computed state.
    // The compiler cannot rematerialize these -> forced register residency.
    float4 acc[C_OUT];
#pragma unroll
    for (int o = 0; o < C_OUT; ++o) acc[o] = make_float4(0.f, 0.f, 0.f, 0.f);

#pragma unroll
    for (int c = 0; c < C_IN; ++c) {
        const float4 x = inB[c * N4 + n4];   // loaded exactly once, transient

        // t[k] = score[k] ⊙ x  (16 v_mul per c)
        float4 t[KK];
#pragma unroll
        for (int k = 0; k < KK; ++k) {
            t[k].x = a[k].x * x.x;
            t[k].y = a[k].y * x.y;
            t[k].z = a[k].z * x.z;
            t[k].w = a[k].w * x.w;
        }

        // acc[o] += w[o,k,c] * t[k]  (256 v_fma per c; w is uniform -> s_load via K$)
#pragma unroll
        for (int o = 0; o < C_OUT; ++o) {
#pragma unroll
            for (int k = 0; k < KK; ++k) {
                const float wv = w[(o * KK + k) * C_IN + c];
                acc[o].x = fmaf(wv, t[k].x, acc[o].x);
                acc[o].y = fmaf(wv, t[k].y, acc[o].y);
                acc[o].z = fmaf(wv, t[k].z, acc[o].z);
                acc[o].w = fmaf(wv, t[k].w, acc[o].w);
            }
        }
    }

    // Output is write-once/streamed: non-temporal keeps inputs resident in L2/L3.
#pragma unroll
    for (int o = 0; o < C_OUT; ++o) {
        vfloat4 v = { acc[o].x, acc[o].y, acc[o].z, acc[o].w };
        __builtin_nontemporal_store(v, reinterpret_cast<vfloat4*>(&outB[o * N4 + n4]));
    }
}

extern "C" void kernel_launch(void* const* d_in, const int* in_sizes, int n_in,
                              void* d_out, int out_size, void* d_ws, size_t ws_size,
                              hipStream_t stream) {
    const float* in = (const float*)d_in[0];   // (B, C_IN, N)
    const float* w  = (const float*)d_in[1];   // (C_OUT, K, C_IN)
    const float* sc = (const float*)d_in[2];   // (B, K, N)
    float* out = (float*)d_out;                // (B, C_OUT, N)

    const int total_threads = B * N4;          // 1,048,576
    const int block = 256;
    const int grid  = total_threads / block;   // 4096
    TransformConv1d_39264591020709_kernel<<<grid, block, 0, stream>>>(in, w, sc, out);
}

// Round 5
// 161.580 us; speedup vs baseline: 10.5515x; 10.5515x over previous
//
#include <hip/hip_runtime.h>

// out[b,o,n] = sum_{k,c} input[b,c,n] * weight[o,k,c] * score[b,k,n]
// B=8, C_IN=16, C_OUT=16, K=4, N=524288. All fp32.
// Compute floor ~58us (9.1 GFLOP @ 157 TF), HBM floor ~68us (426 MB @ 6.3 TB/s).
//
// Round 3 lesson: float4/thread + x[16] live -> compiler (64 VGPR target) remats
// input loads 16x -> L1-BW-bound. Round 4 lesson: forcing residency via acc[16]
// float4 -> compiler allocates 84 VGPR and spills accumulators to scratch = HBM
// (FETCH 4.3 GB, 1.7ms). Fix: scalar per-thread tiling so TOTAL state ~40 VGPR —
// nothing to remat, nothing to spill, robust to the regalloc heuristic.

constexpr int B     = 8;
constexpr int C_IN  = 16;
constexpr int C_OUT = 16;
constexpr int KK    = 4;
constexpr int N     = 524288;   // 2^19

__global__ __launch_bounds__(256) void
TransformConv1d_39264591020709_kernel(const float* __restrict__ in,
                                      const float* __restrict__ w,
                                      const float* __restrict__ sc,
                                      float* __restrict__ out) {
    const int idx = blockIdx.x * blockDim.x + threadIdx.x;   // 0 .. B*N-1
    const int b = idx >> 19;          // idx / N
    const int n = idx & (N - 1);      // idx % N

    const float* inB  = in  + (size_t)b * C_IN  * N + n;
    const float* scB  = sc  + (size_t)b * KK    * N + n;
    float*       outB = out + (size_t)b * C_OUT * N + n;

    // Whole per-thread working set: x[16] + a[4] + acc + p + addrs ≈ 40 VGPR.
    float x[C_IN];
#pragma unroll
    for (int c = 0; c < C_IN; ++c) x[c] = inB[(size_t)c * N];

    float a[KK];
#pragma unroll
    for (int k = 0; k < KK; ++k) a[k] = scB[(size_t)k * N];

#pragma unroll
    for (int o = 0; o < C_OUT; ++o) {
        float acc = 0.f;
#pragma unroll
        for (int k = 0; k < KK; ++k) {
            float p = 0.f;
#pragma unroll
            for (int c = 0; c < C_IN; ++c) {
                const float wv = w[(o * KK + k) * C_IN + c];  // uniform -> s_load via K$
                p = fmaf(wv, x[c], p);
            }
            acc = fmaf(a[k], p, acc);
        }
        // Write-once stream: non-temporal keeps inputs resident in L2/L3.
        __builtin_nontemporal_store(acc, &outB[(size_t)o * N]);
    }
}

extern "C" void kernel_launch(void* const* d_in, const int* in_sizes, int n_in,
                              void* d_out, int out_size, void* d_ws, size_t ws_size,
                              hipStream_t stream) {
    const float* in = (const float*)d_in[0];   // (B, C_IN, N)
    const float* w  = (const float*)d_in[1];   // (C_OUT, K, C_IN)
    const float* sc = (const float*)d_in[2];   // (B, K, N)
    float* out = (float*)d_out;                // (B, C_OUT, N)

    const int total_threads = B * N;           // 4,194,304
    const int block = 256;
    const int grid  = total_threads / block;   // 16384
    TransformConv1d_39264591020709_kernel<<<grid, block, 0, stream>>>(in, w, sc, out);
}